// Round 5
// baseline (592.172 us; speedup 1.0000x reference)
//
#include <hip/hip_runtime.h>

// Correlation cost volume, MAX_DISP=4 (81 displacements).
// out[b,(dy+4)*9+(dx+4),y,x] = (1/C) * sum_c first[b,c,y,x]*second[b,c,y+dy,x+dx]
//
// R5: depth-4 software pipeline. R4 (depth-2, 140us) was latency-bound:
// VALUBusy 20%, occupancy 36%, HBM 13% -- ~170cyc compute slack/iter vs
// 200-900cyc load latency, only 3.4 waves/SIMD TLP. Now: 4 LDS buffers,
// staging regs SaR[4]/SbR[4]/FR[4] rotated by c&3 (constant-indexed after
// #pragma unroll 4 -- the R4-proven SROA-safe pattern; R2's lambda/runtime-
// index spill signature was WRITE_SIZE 506MB, watch it stays ~34.5MB).
// Load for channel c+4 issues at iter c, consumed by ds_write at iter c+3:
// ~3 compute phases (~500cyc) of slack per wave.
// One dy per block, acc = 9 float4. Grid 3x16x36 = 1728 blocks x 128 thr.

#define B_    4
#define C_    128
#define H_    128
#define W_    192
#define HW_   (H_ * W_)
#define CHW_  (C_ * HW_)

#define TX    64    // tile width (pixels)
#define TY    8     // tile height
#define SCOLS 72    // TX + 8 halo
#define SFLOATS (TY * SCOLS)      // 576 floats per channel tile
#define NCHUNK  (SFLOATS / 4)     // 144 float4 chunks

__global__ __launch_bounds__(128, 3)
void corr_kernel(const float* __restrict__ first,
                 const float* __restrict__ second,
                 float* __restrict__ out)
{
    __shared__ float sS[4][SFLOATS];   // 4-deep channel ring, 9216 B

    const int t  = threadIdx.x;
    const int tx = t & 15;       // 0..15 (4 px each)
    const int ty = t >> 4;       // 0..7
    const int x0 = blockIdx.x * TX;
    const int y0 = blockIdx.y * TY;
    const int bz = blockIdx.z;   // b*9 + (dy+4)
    const int b  = bz / 9;
    const int dyi = bz - 9 * b;  // 0..8
    const int dy  = dyi - 4;

    const int X = x0 + 4 * tx;   // this thread's first output x
    const int y = y0 + ty;

    const float* fptr = first + (size_t)b * CHW_ + (size_t)y * W_ + X;

    // --- staging chunk assignment (second tile: TY rows x SCOLS cols) ---
    // chunk k covers LDS floats [4k,4k+4): row = k/18, col4 = k%18.
    // LDS row r <-> output row y0+r, sourced from second row y0+r+dy.
    // Validity is all-or-nothing per 16B chunk (halo=4 floats, W%4==0).
    const int r0 = t / 18, cc0 = t % 18;            // chunk t (all threads)
    const int grow0 = y0 + dy + r0;
    const int gcol0 = x0 - 4 + 4 * cc0;
    const bool v0 = (grow0 >= 0) && (grow0 < H_) && (gcol0 >= 0) && (gcol0 <= W_ - 4);
    const float* sptr0 = second + (size_t)b * CHW_ + (size_t)grow0 * W_ + gcol0;

    const int k1 = 128 + t;                          // chunk 128+t (t<16)
    const bool act1 = (k1 < NCHUNK);
    const int r1 = k1 / 18, cc1 = k1 % 18;
    const int grow1 = y0 + dy + r1;
    const int gcol1 = x0 - 4 + 4 * cc1;
    const bool v1 = act1 && (grow1 >= 0) && (grow1 < H_) && (gcol1 >= 0) && (gcol1 <= W_ - 4);
    const float* sptr1 = second + (size_t)b * CHW_ + (size_t)grow1 * W_ + gcol1;

    const float4 z4 = make_float4(0.f, 0.f, 0.f, 0.f);

    // staging ring: slot k&3 holds channel k from its load until the
    // ds_write at iter k-1 (SaR/SbR) / the FMA block at iter k (FR).
    float4 SaR[4], SbR[4], FR[4];

    // ---- prologue: load channels 0..3; stage channel 0 into buf 0 ----
    #pragma unroll
    for (int u = 0; u < 4; ++u) {
        const size_t co = (size_t)u * HW_;
        SaR[u] = v0 ? *(const float4*)(sptr0 + co) : z4;
        SbR[u] = v1 ? *(const float4*)(sptr1 + co) : z4;
        FR[u]  = *(const float4*)(fptr + co);
    }
    *(float4*)&sS[0][4 * t] = SaR[0];
    if (act1) *(float4*)&sS[0][512 + 4 * t] = SbR[0];

    float4 acc[9];
    #pragma unroll
    for (int i = 0; i < 9; ++i) acc[i] = z4;

    #pragma unroll 4
    for (int c = 0; c < C_; ++c) {
        const int u  = c & 3;          // constant per unrolled copy
        const int u1 = (c + 1) & 3;
        __syncthreads();               // buf[u] ready; iter c-1 reads done

        // current-channel window reads first so FMAs can start ASAP
        const float* srow = &sS[u][ty * SCOLS + 4 * tx];
        float w[12];
        *(float4*)(w + 0) = *(const float4*)(srow);
        *(float4*)(w + 4) = *(const float4*)(srow + 4);
        *(float4*)(w + 8) = *(const float4*)(srow + 8);

        // stage channel c+1 (loaded at iter c-3; vmcnt long satisfied)
        if (c + 1 < C_) {
            *(float4*)&sS[u1][4 * t] = SaR[u1];
            if (act1) *(float4*)&sS[u1][512 + 4 * t] = SbR[u1];
        }

        // issue channel c+4 loads into the slot just retired
        if (c + 4 < C_) {
            const size_t co = (size_t)(c + 4) * HW_;
            SaR[u] = v0 ? *(const float4*)(sptr0 + co) : z4;
            SbR[u] = v1 ? *(const float4*)(sptr1 + co) : z4;
        }

        const float4 fc = FR[u];
        #pragma unroll
        for (int dxi = 0; dxi < 9; ++dxi) {
            acc[dxi].x += fc.x * w[dxi + 0];
            acc[dxi].y += fc.y * w[dxi + 1];
            acc[dxi].z += fc.z * w[dxi + 2];
            acc[dxi].w += fc.w * w[dxi + 3];
        }

        if (c + 4 < C_) FR[u] = *(const float4*)(fptr + (size_t)(c + 4) * HW_);
    }

    // epilogue: out[b, dyi*9 + dxi, y, X..X+3]
    const float scale = 1.0f / (float)C_;
    #pragma unroll
    for (int dxi = 0; dxi < 9; ++dxi) {
        const int d = dyi * 9 + dxi;
        float4 r = acc[dxi];
        r.x *= scale; r.y *= scale; r.z *= scale; r.w *= scale;
        *(float4*)(out + ((size_t)b * 81 + d) * HW_ + (size_t)y * W_ + X) = r;
    }
}

extern "C" void kernel_launch(void* const* d_in, const int* in_sizes, int n_in,
                              void* d_out, int out_size, void* d_ws, size_t ws_size,
                              hipStream_t stream) {
    const float* first  = (const float*)d_in[0];
    const float* second = (const float*)d_in[1];
    float* out = (float*)d_out;

    dim3 grid(W_ / TX, H_ / TY, B_ * 9);   // 3 x 16 x 36 = 1728 blocks
    dim3 block(128);
    corr_kernel<<<grid, block, 0, stream>>>(first, second, out);
}

// Round 6
// 229.668 us; speedup vs baseline: 2.5784x; 2.5784x over previous
//
#include <hip/hip_runtime.h>

// Correlation cost volume, MAX_DISP=4 (81 displacements).
// out[b,(dy+4)*9+(dx+4),y,x] = (1/C) * sum_c first[b,c,y,x]*second[b,c,y+dy,x+dx]
//
// R6: depth-4 pipeline with NAMED registers only. R5's array-based ring
// (SaR[4] indexed by c&3 under pragma-unroll-4) went to scratch: WRITE_SIZE
// 824MB, dur 512us -- this compiler scratch-allocates any loop-indexed local
// array in a barrier loop. R4 (depth-2, named, 140us, WRITE 34.5MB) was
// latency-bound: VALUBusy 20%, ~170cyc slack vs 200-900cyc load latency.
// Here: manual x4-unrolled steady loop (cb=0..120, zero conditionals),
// named Sa0..3/Sb0..3/F0..3, peeled 4-channel tail. Load for channel c+4
// issues at step c, ds_write-consumed at step c+3: ~3 steps (~500cyc) slack.
// One dy per block, acc = 9 float4. Grid 3x16x36 = 1728 blocks x 128 thr.

#define B_    4
#define C_    128
#define H_    128
#define W_    192
#define HW_   (H_ * W_)
#define CHW_  (C_ * HW_)

#define TX    64    // tile width (pixels)
#define TY    8     // tile height
#define SCOLS 72    // TX + 8 halo
#define SFLOATS (TY * SCOLS)      // 576 floats per channel tile
#define NCHUNK  (SFLOATS / 4)     // 144 float4 chunks

__global__ __launch_bounds__(128, 3)
void corr_kernel(const float* __restrict__ first,
                 const float* __restrict__ second,
                 float* __restrict__ out)
{
    __shared__ float sS[4][SFLOATS];   // 4-deep channel ring, 9216 B

    const int t  = threadIdx.x;
    const int tx = t & 15;       // 0..15 (4 px each)
    const int ty = t >> 4;       // 0..7
    const int x0 = blockIdx.x * TX;
    const int y0 = blockIdx.y * TY;
    const int bz = blockIdx.z;   // b*9 + (dy+4)
    const int b  = bz / 9;
    const int dyi = bz - 9 * b;  // 0..8
    const int dy  = dyi - 4;

    const int X = x0 + 4 * tx;   // this thread's first output x
    const int y = y0 + ty;

    const float* fptr = first + (size_t)b * CHW_ + (size_t)y * W_ + X;

    // --- staging chunk assignment (second tile: TY rows x SCOLS cols) ---
    // chunk k covers LDS floats [4k,4k+4): row = k/18, col4 = k%18.
    // LDS row r <-> output row y0+r, sourced from second row y0+r+dy.
    // Validity is all-or-nothing per 16B chunk (halo=4 floats, W%4==0).
    const int r0 = t / 18, cc0 = t % 18;            // chunk t (all threads)
    const int grow0 = y0 + dy + r0;
    const int gcol0 = x0 - 4 + 4 * cc0;
    const bool v0 = (grow0 >= 0) && (grow0 < H_) && (gcol0 >= 0) && (gcol0 <= W_ - 4);
    const float* sptr0 = second + (size_t)b * CHW_ + (size_t)grow0 * W_ + gcol0;

    const int k1 = 128 + t;                          // chunk 128+t (t<16)
    const bool act1 = (k1 < NCHUNK);
    const int r1 = k1 / 18, cc1 = k1 % 18;
    const int grow1 = y0 + dy + r1;
    const int gcol1 = x0 - 4 + 4 * cc1;
    const bool v1 = act1 && (grow1 >= 0) && (grow1 < H_) && (gcol1 >= 0) && (gcol1 <= W_ - 4);
    const float* sptr1 = second + (size_t)b * CHW_ + (size_t)grow1 * W_ + gcol1;

    const float4 z4 = make_float4(0.f, 0.f, 0.f, 0.f);

    // named staging registers -- slot k holds channel cb+k
    float4 Sa0, Sa1, Sa2, Sa3, Sb0, Sb1, Sb2, Sb3, F0, F1, F2, F3;

    // ---- prologue: load channels 0..3; stage channel 0 into sS[0] ----
    Sa0 = v0 ? *(const float4*)(sptr0 + 0 * HW_) : z4;
    Sb0 = v1 ? *(const float4*)(sptr1 + 0 * HW_) : z4;
    F0  = *(const float4*)(fptr + 0 * HW_);
    Sa1 = v0 ? *(const float4*)(sptr0 + 1 * HW_) : z4;
    Sb1 = v1 ? *(const float4*)(sptr1 + 1 * HW_) : z4;
    F1  = *(const float4*)(fptr + 1 * HW_);
    Sa2 = v0 ? *(const float4*)(sptr0 + 2 * HW_) : z4;
    Sb2 = v1 ? *(const float4*)(sptr1 + 2 * HW_) : z4;
    F2  = *(const float4*)(fptr + 2 * HW_);
    Sa3 = v0 ? *(const float4*)(sptr0 + 3 * HW_) : z4;
    Sb3 = v1 ? *(const float4*)(sptr1 + 3 * HW_) : z4;
    F3  = *(const float4*)(fptr + 3 * HW_);
    *(float4*)&sS[0][4 * t] = Sa0;
    if (act1) *(float4*)&sS[0][512 + 4 * t] = Sb0;

    float4 acc[9];
    #pragma unroll
    for (int i = 0; i < 9; ++i) acc[i] = z4;

// one pipeline step: read buf U (channel c), stage buf UN (channel c+1)
// from SaN/SbN, load channel CNEXT into SaU/SbU/FU, FMA with old FU.
#define STEP(U, UN, SaN, SbN, SaU, SbU, FU, CNEXT)                      \
    {                                                                   \
        __syncthreads();                                                \
        const float* srow = &sS[U][ty * SCOLS + 4 * tx];                \
        float w[12];                                                    \
        *(float4*)(w + 0) = *(const float4*)(srow);                     \
        *(float4*)(w + 4) = *(const float4*)(srow + 4);                 \
        *(float4*)(w + 8) = *(const float4*)(srow + 8);                 \
        *(float4*)&sS[UN][4 * t] = SaN;                                 \
        if (act1) *(float4*)&sS[UN][512 + 4 * t] = SbN;                 \
        const float4 fc = FU;                                           \
        const size_t co = (size_t)(CNEXT) * HW_;                        \
        SaU = v0 ? *(const float4*)(sptr0 + co) : z4;                   \
        SbU = v1 ? *(const float4*)(sptr1 + co) : z4;                   \
        FU  = *(const float4*)(fptr + co);                              \
        _Pragma("unroll")                                               \
        for (int dxi = 0; dxi < 9; ++dxi) {                             \
            acc[dxi].x += fc.x * w[dxi + 0];                            \
            acc[dxi].y += fc.y * w[dxi + 1];                            \
            acc[dxi].z += fc.z * w[dxi + 2];                            \
            acc[dxi].w += fc.w * w[dxi + 3];                            \
        }                                                               \
    }

// tail step: no new loads; optional stage
#define STEPT(U, UN, SaN, SbN, FU)                                      \
    {                                                                   \
        __syncthreads();                                                \
        const float* srow = &sS[U][ty * SCOLS + 4 * tx];                \
        float w[12];                                                    \
        *(float4*)(w + 0) = *(const float4*)(srow);                     \
        *(float4*)(w + 4) = *(const float4*)(srow + 4);                 \
        *(float4*)(w + 8) = *(const float4*)(srow + 8);                 \
        *(float4*)&sS[UN][4 * t] = SaN;                                 \
        if (act1) *(float4*)&sS[UN][512 + 4 * t] = SbN;                 \
        const float4 fc = FU;                                           \
        _Pragma("unroll")                                               \
        for (int dxi = 0; dxi < 9; ++dxi) {                             \
            acc[dxi].x += fc.x * w[dxi + 0];                            \
            acc[dxi].y += fc.y * w[dxi + 1];                            \
            acc[dxi].z += fc.z * w[dxi + 2];                            \
            acc[dxi].w += fc.w * w[dxi + 3];                            \
        }                                                               \
    }

#define STEPL(U, FU)                                                    \
    {                                                                   \
        __syncthreads();                                                \
        const float* srow = &sS[U][ty * SCOLS + 4 * tx];                \
        float w[12];                                                    \
        *(float4*)(w + 0) = *(const float4*)(srow);                     \
        *(float4*)(w + 4) = *(const float4*)(srow + 4);                 \
        *(float4*)(w + 8) = *(const float4*)(srow + 8);                 \
        const float4 fc = FU;                                           \
        _Pragma("unroll")                                               \
        for (int dxi = 0; dxi < 9; ++dxi) {                             \
            acc[dxi].x += fc.x * w[dxi + 0];                            \
            acc[dxi].y += fc.y * w[dxi + 1];                            \
            acc[dxi].z += fc.z * w[dxi + 2];                            \
            acc[dxi].w += fc.w * w[dxi + 3];                            \
        }                                                               \
    }

    // ---- steady state: channels 0..123, no conditionals ----
    #pragma unroll 1
    for (int cb = 0; cb < 124; cb += 4) {
        STEP(0, 1, Sa1, Sb1, Sa0, Sb0, F0, cb + 4)
        STEP(1, 2, Sa2, Sb2, Sa1, Sb1, F1, cb + 5)
        STEP(2, 3, Sa3, Sb3, Sa2, Sb2, F2, cb + 6)
        STEP(3, 0, Sa0, Sb0, Sa3, Sb3, F3, cb + 7)
    }
    // ---- tail: channels 124..127 (slots already loaded; sS[0] holds 124) ----
    STEPT(0, 1, Sa1, Sb1, F0)
    STEPT(1, 2, Sa2, Sb2, F1)
    STEPT(2, 3, Sa3, Sb3, F2)
    STEPL(3, F3)

    // epilogue: out[b, dyi*9 + dxi, y, X..X+3]
    const float scale = 1.0f / (float)C_;
    #pragma unroll
    for (int dxi = 0; dxi < 9; ++dxi) {
        const int d = dyi * 9 + dxi;
        float4 r = acc[dxi];
        r.x *= scale; r.y *= scale; r.z *= scale; r.w *= scale;
        *(float4*)(out + ((size_t)b * 81 + d) * HW_ + (size_t)y * W_ + X) = r;
    }
}

extern "C" void kernel_launch(void* const* d_in, const int* in_sizes, int n_in,
                              void* d_out, int out_size, void* d_ws, size_t ws_size,
                              hipStream_t stream) {
    const float* first  = (const float*)d_in[0];
    const float* second = (const float*)d_in[1];
    float* out = (float*)d_out;

    dim3 grid(W_ / TX, H_ / TY, B_ * 9);   // 3 x 16 x 36 = 1728 blocks
    dim3 block(128);
    corr_kernel<<<grid, block, 0, stream>>>(first, second, out);
}

// Round 7
// 207.653 us; speedup vs baseline: 2.8517x; 1.1060x over previous
//
#include <hip/hip_runtime.h>

// Correlation cost volume, MAX_DISP=4 (81 displacements).
// out[b,(dy+4)*9+(dx+4),y,x] = (1/C) * sum_c first[b,c,y,x]*second[b,c,y+dy,x+dx]
//
// R7: BARRIER-FREE. R4(depth-2)=R6(depth-4)=139us proved the bottleneck is
// __syncthreads' forced s_waitcnt vmcnt(0) drain: every per-channel barrier
// drains the prefetch queue, so pipeline depth beyond one step is useless
// (~2600cyc wall/step vs ~180cyc issue work). LDS staging is what forced the
// barrier -> drop LDS entirely. Each thread loads its own 12-float window
// (3x float4) + first float4 per channel; adjacent lanes overlap 3x in L1/L2.
// Depth-4 named-register pipeline (R6-proven spill-safe macro pattern), zero
// barriers -> compiler emits only fine-grained vmcnt(N); ~3 steps of slack.
// One dy per block, acc = 9 float4. Grid 3x16x36 = 1728 blocks x 128 thr.

#define B_    4
#define C_    128
#define H_    128
#define W_    192
#define HW_   (H_ * W_)
#define CHW_  (C_ * HW_)

#define TX    64    // tile width (pixels)
#define TY    8     // tile height

__global__ __launch_bounds__(128, 3)
void corr_kernel(const float* __restrict__ first,
                 const float* __restrict__ second,
                 float* __restrict__ out)
{
    const int t  = threadIdx.x;
    const int tx = t & 15;       // 0..15 (4 px each)
    const int ty = t >> 4;       // 0..7
    const int x0 = blockIdx.x * TX;
    const int y0 = blockIdx.y * TY;
    const int bz = blockIdx.z;   // b*9 + (dy+4)
    const int b  = bz / 9;
    const int dyi = bz - 9 * b;  // 0..8
    const int dy  = dyi - 4;

    const int X = x0 + 4 * tx;   // this thread's first output x
    const int y = y0 + ty;
    const int ys = y + dy;       // source row in second

    const float* fptr = first + (size_t)b * CHW_ + (size_t)y * W_ + X;
    // window base: second[b, c, ys, X-4] (guarded; only deref'd when valid)
    const float* wptr = second + (size_t)b * CHW_ + (size_t)ys * W_ + (X - 4);

    const bool rowv = (ys >= 0) && (ys < H_);
    const bool v0 = rowv && (X >= 4);          // chunk [X-4, X)
    const bool v1 = rowv;                      // chunk [X,   X+4)   always in 0..W-4
    const bool v2 = rowv && (X <= W_ - 8);     // chunk [X+4, X+8)

    const float4 z4 = make_float4(0.f, 0.f, 0.f, 0.f);

    // named pipeline slots: slot K holds channel cb+K's window + first frag
    float4 A0, A1, A2, AF, B0, B1, B2, BF, C0, C1, C2, CF, D0, D1, D2, DF;

    // prologue: load channels 0..3
    A0 = v0 ? *(const float4*)(wptr + 0 * HW_)     : z4;
    A1 = v1 ? *(const float4*)(wptr + 0 * HW_ + 4) : z4;
    A2 = v2 ? *(const float4*)(wptr + 0 * HW_ + 8) : z4;
    AF = *(const float4*)(fptr + 0 * HW_);
    B0 = v0 ? *(const float4*)(wptr + 1 * HW_)     : z4;
    B1 = v1 ? *(const float4*)(wptr + 1 * HW_ + 4) : z4;
    B2 = v2 ? *(const float4*)(wptr + 1 * HW_ + 8) : z4;
    BF = *(const float4*)(fptr + 1 * HW_);
    C0 = v0 ? *(const float4*)(wptr + 2 * HW_)     : z4;
    C1 = v1 ? *(const float4*)(wptr + 2 * HW_ + 4) : z4;
    C2 = v2 ? *(const float4*)(wptr + 2 * HW_ + 8) : z4;
    CF = *(const float4*)(fptr + 2 * HW_);
    D0 = v0 ? *(const float4*)(wptr + 3 * HW_)     : z4;
    D1 = v1 ? *(const float4*)(wptr + 3 * HW_ + 4) : z4;
    D2 = v2 ? *(const float4*)(wptr + 3 * HW_ + 8) : z4;
    DF = *(const float4*)(fptr + 3 * HW_);

    float4 acc[9];
    #pragma unroll
    for (int i = 0; i < 9; ++i) acc[i] = z4;

// one step: snapshot slot (w[12] is SROA'd to pure register renames), issue
// channel CN's loads into the slot (they fly for ~3 more steps), then FMA.
#define STEP(P0, P1, P2, PF, CN)                                        \
    {                                                                   \
        float w[12];                                                    \
        *(float4*)(w + 0) = P0;                                         \
        *(float4*)(w + 4) = P1;                                         \
        *(float4*)(w + 8) = P2;                                         \
        const float4 fc = PF;                                           \
        const size_t co = (size_t)(CN) * HW_;                           \
        P0 = v0 ? *(const float4*)(wptr + co)     : z4;                 \
        P1 = v1 ? *(const float4*)(wptr + co + 4) : z4;                 \
        P2 = v2 ? *(const float4*)(wptr + co + 8) : z4;                 \
        PF = *(const float4*)(fptr + co);                               \
        _Pragma("unroll")                                               \
        for (int dxi = 0; dxi < 9; ++dxi) {                             \
            acc[dxi].x += fc.x * w[dxi + 0];                            \
            acc[dxi].y += fc.y * w[dxi + 1];                            \
            acc[dxi].z += fc.z * w[dxi + 2];                            \
            acc[dxi].w += fc.w * w[dxi + 3];                            \
        }                                                               \
    }

// tail step: FMA only
#define STEPL(P0, P1, P2, PF)                                           \
    {                                                                   \
        float w[12];                                                    \
        *(float4*)(w + 0) = P0;                                         \
        *(float4*)(w + 4) = P1;                                         \
        *(float4*)(w + 8) = P2;                                         \
        const float4 fc = PF;                                           \
        _Pragma("unroll")                                               \
        for (int dxi = 0; dxi < 9; ++dxi) {                             \
            acc[dxi].x += fc.x * w[dxi + 0];                            \
            acc[dxi].y += fc.y * w[dxi + 1];                            \
            acc[dxi].z += fc.z * w[dxi + 2];                            \
            acc[dxi].w += fc.w * w[dxi + 3];                            \
        }                                                               \
    }

    // steady state: channels 0..123, loads run 4 ahead, no barriers anywhere
    #pragma unroll 1
    for (int cb = 0; cb < 124; cb += 4) {
        STEP(A0, A1, A2, AF, cb + 4)
        STEP(B0, B1, B2, BF, cb + 5)
        STEP(C0, C1, C2, CF, cb + 6)
        STEP(D0, D1, D2, DF, cb + 7)
    }
    // tail: channels 124..127 already in slots
    STEPL(A0, A1, A2, AF)
    STEPL(B0, B1, B2, BF)
    STEPL(C0, C1, C2, CF)
    STEPL(D0, D1, D2, DF)

    // epilogue: out[b, dyi*9 + dxi, y, X..X+3]
    const float scale = 1.0f / (float)C_;
    #pragma unroll
    for (int dxi = 0; dxi < 9; ++dxi) {
        const int d = dyi * 9 + dxi;
        float4 r = acc[dxi];
        r.x *= scale; r.y *= scale; r.z *= scale; r.w *= scale;
        *(float4*)(out + ((size_t)b * 81 + d) * HW_ + (size_t)y * W_ + X) = r;
    }
}

extern "C" void kernel_launch(void* const* d_in, const int* in_sizes, int n_in,
                              void* d_out, int out_size, void* d_ws, size_t ws_size,
                              hipStream_t stream) {
    const float* first  = (const float*)d_in[0];
    const float* second = (const float*)d_in[1];
    float* out = (float*)d_out;

    dim3 grid(W_ / TX, H_ / TY, B_ * 9);   // 3 x 16 x 36 = 1728 blocks
    dim3 block(128);
    corr_kernel<<<grid, block, 0, stream>>>(first, second, out);
}